// Round 1
// baseline (190.663 us; speedup 1.0000x reference)
//
#include <hip/hip_runtime.h>
#include <hip/hip_bf16.h>

typedef __attribute__((ext_vector_type(8))) short bf16x8;
typedef __attribute__((ext_vector_type(4))) float f32x4;
typedef unsigned short u16;

constexpr int NSEQ = 16384;
constexpr int KD   = 4096;
constexpr int NQ   = 512;     // q cols
constexpr int NCOL = 640;     // q (512) + k (128)
constexpr int BM   = 64;
constexpr int BK   = 64;
constexpr int NKSTEP = KD / BK;                      // 64
constexpr int CHUNKS_PER_TILE = NCOL * BK * 2 / 16;  // 5120 chunks of 16B
constexpr int TOTAL_CHUNKS = CHUNKS_PER_TILE * NKSTEP;

// ---- f32 -> bf16 (RTNE) pack helpers -------------------------------------
__device__ __forceinline__ unsigned bf_round(float x) {
    unsigned u = __builtin_bit_cast(unsigned, x);
    unsigned r = u + 0x7FFFu + ((u >> 16) & 1u);
    return r >> 16;
}
__device__ __forceinline__ unsigned pk2(float lo, float hi) {
    return bf_round(lo) | (bf_round(hi) << 16);
}

// ---- Kernel 1: convert W (q_w ++ k_w) f32 -> bf16, pre-swizzled chunks ----
// Staged layout: tile kk (K-window of 64), chunk c in [0,5120):
//   n = c>>3, s = c&7, k0 = kk*64 + ((s ^ (n&7))<<3)
//   chunk holds W[n][k0 .. k0+8)
// so that linear global_load_lds (chunk c -> LDS byte c*16) gives LDS layout
//   element (n,k) at byte n*128 + ((k*2) ^ ((n&7)<<4))
__global__ __launch_bounds__(256) void wconv_kernel(
    const float* __restrict__ qw, const float* __restrict__ kw,
    u16* __restrict__ Wst)
{
    int cg = blockIdx.x * 256 + threadIdx.x;
    int kk = cg / CHUNKS_PER_TILE;
    int c  = cg - kk * CHUNKS_PER_TILE;
    int n  = c >> 3;
    int s  = c & 7;
    int k0 = kk * BK + ((s ^ (n & 7)) << 3);
    const float* src = (n < NQ) ? (qw + (size_t)n * KD + k0)
                                : (kw + (size_t)(n - NQ) * KD + k0);
    float4 v0 = *(const float4*)(src);
    float4 v1 = *(const float4*)(src + 4);
    int4 o;
    o.x = (int)pk2(v0.x, v0.y);
    o.y = (int)pk2(v0.z, v0.w);
    o.z = (int)pk2(v1.x, v1.y);
    o.w = (int)pk2(v1.z, v1.w);
    *(int4*)(Wst + (size_t)cg * 8) = o;
}

// ---- Kernel 2: GEMM P[n,640] = h[n,4096] @ W[640,4096]^T (bf16 MFMA) -----
__global__ __launch_bounds__(512, 2) void gemm_kernel(
    const float* __restrict__ hid, const u16* __restrict__ Wst,
    float* __restrict__ P)
{
    __shared__ char smem[NCOL * BK * 2 + BM * BK * 2];   // 80KB B + 8KB A
    char* sB = smem;
    char* sA = smem + NCOL * BK * 2;

    const int t    = threadIdx.x;
    const int lane = t & 63;
    const int wid  = t >> 6;        // 0..7
    const int wm   = wid >> 2;      // 0..1 : M half (32 rows)
    const int wq   = wid & 3;       // 0..3 : N quarter (160 cols)
    const int row0 = blockIdx.x * BM;

    f32x4 acc[2][10] = {};

    // A staging: thread t handles tile row ar, k-slot as (8 f32 -> 8 bf16)
    const int ar = t >> 3;
    const int as = t & 7;
    const float* gA = hid + (size_t)(row0 + ar) * KD + (as << 3);
    char* aDst = sA + ar * (BK * 2) + ((as * 16) ^ ((ar & 7) << 4));

    // fragment read params
    const int bn  = lane & 15;
    const int kb8 = (lane >> 4) << 3;      // 0,8,16,24
    const int swz = (bn & 7) << 4;

    char* bLdsBase = sB + wid * 64 * 16;   // wave-uniform glds dest base

    // prefetch first A chunk
    float4 v0 = *(const float4*)(gA);
    float4 v1 = *(const float4*)(gA + 4);

    for (int kk = 0; kk < NKSTEP; ++kk) {
        // stage B: 10 x global_load_lds dwordx4 per thread (linear dest)
        const u16* tile = Wst + (size_t)kk * (CHUNKS_PER_TILE * 8);
        #pragma unroll
        for (int it = 0; it < 10; ++it) {
            __builtin_amdgcn_global_load_lds(
                (const __attribute__((address_space(1))) void*)(tile + (size_t)(it * 512 + t) * 8),
                (__attribute__((address_space(3))) void*)(bLdsBase + it * 512 * 16),
                16, 0, 0);
        }
        // stage A: cvt prefetched f32x8 -> bf16x8, swizzled ds_write_b128
        int4 ap;
        ap.x = (int)pk2(v0.x, v0.y);
        ap.y = (int)pk2(v0.z, v0.w);
        ap.z = (int)pk2(v1.x, v1.y);
        ap.w = (int)pk2(v1.z, v1.w);
        *(int4*)aDst = ap;

        __syncthreads();

        // prefetch next A chunk during compute phase
        if (kk + 1 < NKSTEP) {
            v0 = *(const float4*)(gA + (kk + 1) * BK);
            v1 = *(const float4*)(gA + (kk + 1) * BK + 4);
        }

        #pragma unroll
        for (int ks = 0; ks < 2; ++ks) {
            const int k2 = ks * 64 + kb8 * 2;       // byte offset of k within row
            const int ko = k2 ^ swz;
            bf16x8 a0 = *(const bf16x8*)(sA + (wm * 32 + bn) * 128 + ko);
            bf16x8 a1 = *(const bf16x8*)(sA + (wm * 32 + 16 + bn) * 128 + ko);
            bf16x8 bf[10];
            #pragma unroll
            for (int f = 0; f < 10; ++f) {
                const int nn = wq * 160 + f * 16 + bn;
                bf[f] = *(const bf16x8*)(sB + nn * 128 + ko);
            }
            #pragma unroll
            for (int f = 0; f < 10; ++f) {
                acc[0][f] = __builtin_amdgcn_mfma_f32_16x16x32_bf16(a0, bf[f], acc[0][f], 0, 0, 0);
                acc[1][f] = __builtin_amdgcn_mfma_f32_16x16x32_bf16(a1, bf[f], acc[1][f], 0, 0, 0);
            }
        }
        __syncthreads();
    }

    // epilogue: write P (f32). C/D layout: col=lane&15, row=(lane>>4)*4+j
    const int crow = (lane >> 4) << 2;
    const int ccol = lane & 15;
    #pragma unroll
    for (int mi = 0; mi < 2; ++mi) {
        #pragma unroll
        for (int f = 0; f < 10; ++f) {
            #pragma unroll
            for (int j = 0; j < 4; ++j) {
                int r  = row0 + wm * 32 + mi * 16 + crow + j;
                int cc = wq * 160 + f * 16 + ccol;
                P[(size_t)r * NCOL + cc] = acc[mi][f][j];
            }
        }
    }
}

// ---- Kernel 3: gating epilogue -------------------------------------------
// thread per (token, head, group): tid bits [5..]=tok, [4:2]=h, [1:0]=g
__global__ __launch_bounds__(256) void gate_kernel(
    const float* __restrict__ P, const float* __restrict__ qb,
    const float* __restrict__ qnw, const float* __restrict__ knw,
    const float* __restrict__ kbase, const float* __restrict__ bb,
    float* __restrict__ out)
{
    __shared__ float skb[8 * 16 * 16];
    __shared__ float sqb[512];
    __shared__ float sb[32];
    __shared__ float snw[32];

    int tid = threadIdx.x;
    for (int i = tid; i < 2048; i += 256) skb[i] = kbase[i];
    for (int i = tid; i < 512;  i += 256) sqb[i] = qb[i];
    if (tid < 32) sb[tid] = bb[tid];
    if (tid < 16) snw[tid] = qnw[tid];
    else if (tid < 32) snw[tid] = knw[tid - 16];
    __syncthreads();

    int gid = blockIdx.x * 256 + tid;
    int tok = gid >> 5;
    int hh  = (gid >> 2) & 7;
    int g   = gid & 3;

    const float* prow = P + (size_t)tok * NCOL;
    const int qoff = (hh * 4 + g) * 16;

    // q row + bias, RMSNorm
    float q[16];
    float ss = 0.f;
    {
        const float4* qp = (const float4*)(prow + qoff);
        const float4* bp = (const float4*)(sqb + qoff);
        #pragma unroll
        for (int i = 0; i < 4; ++i) {
            float4 v = qp[i], b4 = bp[i];
            q[4*i+0] = v.x + b4.x; q[4*i+1] = v.y + b4.y;
            q[4*i+2] = v.z + b4.z; q[4*i+3] = v.w + b4.w;
        }
        #pragma unroll
        for (int d = 0; d < 16; ++d) ss += q[d] * q[d];
    }
    float rq = rsqrtf(ss * (1.f / 16.f) + 1e-6f);
    #pragma unroll
    for (int d = 0; d < 16; ++d) q[d] *= rq * snw[d];

    // k row, RMSNorm
    float k[16];
    float sk = 0.f;
    {
        const float4* kp = (const float4*)(prow + NQ + hh * 16);
        #pragma unroll
        for (int i = 0; i < 4; ++i) {
            float4 v = kp[i];
            k[4*i+0] = v.x; k[4*i+1] = v.y; k[4*i+2] = v.z; k[4*i+3] = v.w;
        }
        #pragma unroll
        for (int d = 0; d < 16; ++d) sk += k[d] * k[d];
    }
    float rk = rsqrtf(sk * (1.f / 16.f) + 1e-6f);

    // logit = k̂·q̂ / 4 + b
    float logit = 0.f;
    #pragma unroll
    for (int d = 0; d < 16; ++d) logit += (k[d] * rk * snw[16 + d]) * q[d];
    logit = logit * 0.25f + sb[hh * 4 + g];

    // sum over sink tokens
    float accum = 0.f;
    const float* kbh = skb + hh * 256;
    #pragma unroll
    for (int s = 0; s < 16; ++s) {
        float lb = 0.f;
        #pragma unroll
        for (int d = 0; d < 16; ++d) lb += kbh[s * 16 + d] * q[d];
        accum += __expf(lb * 0.25f - logit);
    }
    float r = 1.f / (1.f + accum);

    // mean over g (4 lanes), lane g==0 writes
    r += __shfl_xor(r, 1);
    r += __shfl_xor(r, 2);
    if (g == 0) out[(size_t)hh * NSEQ + tok] = r * 0.25f;
}

// ---- launch ---------------------------------------------------------------
extern "C" void kernel_launch(void* const* d_in, const int* in_sizes, int n_in,
                              void* d_out, int out_size, void* d_ws, size_t ws_size,
                              hipStream_t stream)
{
    const float* hid = (const float*)d_in[0];
    const float* qw  = (const float*)d_in[1];
    const float* qb  = (const float*)d_in[2];
    const float* kw  = (const float*)d_in[3];
    const float* qnw = (const float*)d_in[4];
    const float* knw = (const float*)d_in[5];
    const float* kb  = (const float*)d_in[6];
    const float* bb  = (const float*)d_in[7];
    float* out = (float*)d_out;

    u16*   Wst = (u16*)d_ws;                                    // 5,242,880 B
    float* P   = (float*)((char*)d_ws + (size_t)NCOL * KD * 2); // 41,943,040 B

    wconv_kernel<<<TOTAL_CHUNKS / 256, 256, 0, stream>>>(qw, kw, Wst);
    gemm_kernel<<<NSEQ / BM, 512, 0, stream>>>(hid, Wst, P);
    gate_kernel<<<NSEQ * 32 / 256, 256, 0, stream>>>(P, qb, qnw, knw, kb, bb, out);
}

// Round 2
// 186.789 us; speedup vs baseline: 1.0207x; 1.0207x over previous
//
#include <hip/hip_runtime.h>
#include <hip/hip_bf16.h>

typedef __attribute__((ext_vector_type(8))) short bf16x8;
typedef __attribute__((ext_vector_type(4))) float f32x4;
typedef unsigned short u16;

constexpr int NSEQ = 16384;
constexpr int KD   = 4096;
constexpr int NQ   = 512;     // q cols
constexpr int NCOL = 640;     // q (512) + k (128)
constexpr int BM   = 128;
constexpr int BK   = 32;
constexpr int KHALF = 2048;
constexpr int NKS  = KHALF / BK;                     // 64 K-steps per block
constexpr int CHUNKS_PER_TILE = NCOL * BK * 2 / 16;  // 2560 chunks of 16B
constexpr int NTILES = KD / BK;                      // 128
constexpr int TOTAL_CHUNKS = CHUNKS_PER_TILE * NTILES;
constexpr int TILE_U16 = CHUNKS_PER_TILE * 8;        // 20480 u16 per tile
constexpr int BUF_BYTES = 49152;                     // 40960 B-tile + 8192 A-tile

// ---- f32 -> bf16 (RTNE) pack helpers -------------------------------------
__device__ __forceinline__ unsigned bf_round(float x) {
    unsigned u = __builtin_bit_cast(unsigned, x);
    unsigned r = u + 0x7FFFu + ((u >> 16) & 1u);
    return r >> 16;
}
__device__ __forceinline__ unsigned pk2(float lo, float hi) {
    return bf_round(lo) | (bf_round(hi) << 16);
}
__device__ __forceinline__ float bfu(unsigned u) {
    return __builtin_bit_cast(float, u << 16);
}

// ---- Kernel 1: convert W (q_w ++ k_w) f32 -> bf16, pre-swizzled chunks ----
// Tile kk (K-window of 32), chunk c in [0,2560): n = c>>2, s = c&3,
// content k0 = kk*32 + ((s ^ (n&3))<<3). Linear glds => LDS layout:
// element (n, kslot ks) 16B chunk at byte n*64 + ((ks*16) ^ ((n&3)<<4)).
__global__ __launch_bounds__(256) void wconv_kernel(
    const float* __restrict__ qw, const float* __restrict__ kw,
    u16* __restrict__ Wst)
{
    int cg = blockIdx.x * 256 + threadIdx.x;
    int kk = cg / CHUNKS_PER_TILE;
    int c  = cg - kk * CHUNKS_PER_TILE;
    int n  = c >> 2;
    int s  = c & 3;
    int k0 = kk * BK + ((s ^ (n & 3)) << 3);
    const float* src = (n < NQ) ? (qw + (size_t)n * KD + k0)
                                : (kw + (size_t)(n - NQ) * KD + k0);
    float4 v0 = *(const float4*)(src);
    float4 v1 = *(const float4*)(src + 4);
    int4 o;
    o.x = (int)pk2(v0.x, v0.y);
    o.y = (int)pk2(v0.z, v0.w);
    o.z = (int)pk2(v1.x, v1.y);
    o.w = (int)pk2(v1.z, v1.w);
    *(int4*)(Wst + (size_t)cg * 8) = o;
}

// ---- Kernel 2: K-split GEMM, bf16 partial P ------------------------------
// grid 256 = 128 M-blocks x 2 K-halves. BM=128, BN=640, BK=32.
// 8 waves: wm (0..1) x wq (0..3), wave tile 64 rows x 160 cols.
// Double-buffered LDS, counted vmcnt, raw s_barrier (1 per K-step).
__global__ __launch_bounds__(512, 2) void gemm_kernel(
    const float* __restrict__ hid, const u16* __restrict__ Wst,
    u16* __restrict__ P0, u16* __restrict__ P1)
{
    __shared__ char smem[2 * BUF_BYTES];

    const int t    = threadIdx.x;
    const int lane = t & 63;
    const int wid  = t >> 6;
    const int wm   = wid >> 2;
    const int wq   = wid & 3;
    const int mblk = blockIdx.x & 127;
    const int kh   = blockIdx.x >> 7;
    const int row0 = mblk * BM;

    const float* hk   = hid + (size_t)row0 * KD + kh * KHALF;
    const u16*  wbase = Wst + (size_t)(kh * NKS) * TILE_U16;
    u16* P = kh ? P1 : P0;

    f32x4 acc[4][10] = {};

    // A staging: thread t -> row ar (0..127), k-slot ks8 (0..3), 8 f32
    const int ar  = t >> 2;
    const int ks8 = t & 3;
    const float* gA = hk + (size_t)ar * KD + ks8 * 8;
    const int aWoff = ar * 64 + ((ks8 * 16) ^ ((ar & 3) << 4));

    // fragment read params
    const int bn    = lane & 15;
    const int kslot = lane >> 4;
    const int koff  = (kslot * 16) ^ ((bn & 3) << 4);

    float4 vA0a, vA0b, vA1a, vA1b;

    // ---- prologue: A-loads first (so ds_write's implicit wait leaves glds
    // in flight), then glds(0), then ds_write A(0) ----
    vA0a = *(const float4*)(gA);            // A(0)
    vA0b = *(const float4*)(gA + 4);
    vA1a = *(const float4*)(gA + BK);       // A(1)
    vA1b = *(const float4*)(gA + BK + 4);
    {
        const u16* tile = wbase;
        #pragma unroll
        for (int it = 0; it < 5; ++it)
            __builtin_amdgcn_global_load_lds(
                (const __attribute__((address_space(1))) void*)(tile + (size_t)(it * 512 + t) * 8),
                (__attribute__((address_space(3))) void*)(smem + wid * 1024 + it * 8192),
                16, 0, 0);
    }
    {
        int4 ap;
        ap.x = (int)pk2(vA0a.x, vA0a.y);
        ap.y = (int)pk2(vA0a.z, vA0a.w);
        ap.z = (int)pk2(vA0b.x, vA0b.y);
        ap.w = (int)pk2(vA0b.z, vA0b.w);
        *(int4*)(smem + 40960 + aWoff) = ap;
    }
    asm volatile("s_waitcnt lgkmcnt(0)" ::: "memory");
    __builtin_amdgcn_s_barrier();

#define GSTEP(tt, VAWa, VAWb, VALa, VALb)                                        \
    do {                                                                         \
        const int cur_ = (tt) & 1;                                               \
        char* sBc = smem + cur_ * BUF_BYTES;                                     \
        char* sAc = sBc + 40960;                                                 \
        if ((tt) < NKS - 1) {                                                    \
            char* sBn = smem + (cur_ ^ 1) * BUF_BYTES;                           \
            const u16* tile = wbase + (size_t)((tt) + 1) * TILE_U16;             \
            _Pragma("unroll")                                                    \
            for (int it = 0; it < 5; ++it)                                       \
                __builtin_amdgcn_global_load_lds(                                \
                    (const __attribute__((address_space(1))) void*)(tile + (size_t)(it * 512 + t) * 8), \
                    (__attribute__((address_space(3))) void*)(sBn + wid * 1024 + it * 8192), \
                    16, 0, 0);                                                   \
            {                                                                    \
                int4 ap;                                                         \
                ap.x = (int)pk2(VAWa.x, VAWa.y);                                 \
                ap.y = (int)pk2(VAWa.z, VAWa.w);                                 \
                ap.z = (int)pk2(VAWb.x, VAWb.y);                                 \
                ap.w = (int)pk2(VAWb.z, VAWb.w);                                 \
                *(int4*)(sBn + 40960 + aWoff) = ap;                              \
            }                                                                    \
            if ((tt) < NKS - 2) {                                                \
                VALa = *(const float4*)(gA + ((tt) + 2) * BK);                   \
                VALb = *(const float4*)(gA + ((tt) + 2) * BK + 4);               \
                asm volatile("s_waitcnt vmcnt(7)" ::: "memory");                 \
            } else {                                                             \
                asm volatile("s_waitcnt vmcnt(5)" ::: "memory");                 \
            }                                                                    \
        } else {                                                                 \
            asm volatile("s_waitcnt vmcnt(0)" ::: "memory");                     \
        }                                                                        \
        bf16x8 af[4];                                                            \
        _Pragma("unroll")                                                        \
        for (int m = 0; m < 4; ++m)                                              \
            af[m] = *(const bf16x8*)(sAc + (wm * 64 + m * 16 + bn) * 64 + koff); \
        _Pragma("unroll")                                                        \
        for (int f = 0; f < 10; ++f) {                                           \
            bf16x8 bfr = *(const bf16x8*)(sBc + (wq * 160 + f * 16 + bn) * 64 + koff); \
            _Pragma("unroll")                                                    \
            for (int m = 0; m < 4; ++m)                                          \
                acc[m][f] = __builtin_amdgcn_mfma_f32_16x16x32_bf16(af[m], bfr, acc[m][f], 0, 0, 0); \
        }                                                                        \
        if ((tt) < NKS - 1) {                                                    \
            asm volatile("s_waitcnt lgkmcnt(0)" ::: "memory");                   \
            __builtin_amdgcn_s_barrier();                                        \
        }                                                                        \
    } while (0)

    for (int t2 = 0; t2 < NKS / 2; ++t2) {
        const int tt = 2 * t2;
        GSTEP(tt,     vA1a, vA1b, vA0a, vA0b);  // write A(tt+1) [odd->vA1], load A(tt+2) [even->vA0]
        GSTEP(tt + 1, vA0a, vA0b, vA1a, vA1b);
    }
#undef GSTEP

    // epilogue: bf16 partial-P write. C/D: col=lane&15, row=(lane>>4)*4+j
    const int crow = (lane >> 4) << 2;
    const int ccol = lane & 15;
    u16* Pp = P + (size_t)(row0 + wm * 64) * NCOL + wq * 160 + ccol;
    #pragma unroll
    for (int m = 0; m < 4; ++m)
        #pragma unroll
        for (int f = 0; f < 10; ++f)
            #pragma unroll
            for (int j = 0; j < 4; ++j)
                Pp[(size_t)(m * 16 + crow + j) * NCOL + f * 16] =
                    (u16)bf_round(acc[m][f][j]);
}

// ---- Kernel 3: gating epilogue (reads two bf16 partial-P halves) ----------
__global__ __launch_bounds__(256) void gate_kernel(
    const u16* __restrict__ P0, const u16* __restrict__ P1,
    const float* __restrict__ qb,
    const float* __restrict__ qnw, const float* __restrict__ knw,
    const float* __restrict__ kbase, const float* __restrict__ bb,
    float* __restrict__ out)
{
    __shared__ float skb[8 * 16 * 16];
    __shared__ float sqb[512];
    __shared__ float sb[32];
    __shared__ float snw[32];

    int tid = threadIdx.x;
    for (int i = tid; i < 2048; i += 256) skb[i] = kbase[i];
    for (int i = tid; i < 512;  i += 256) sqb[i] = qb[i];
    if (tid < 32) sb[tid] = bb[tid];
    if (tid < 16) snw[tid] = qnw[tid];
    else if (tid < 32) snw[tid] = knw[tid - 16];
    __syncthreads();

    int gid = blockIdx.x * 256 + tid;
    int tok = gid >> 5;
    int hh  = (gid >> 2) & 7;
    int g   = gid & 3;

    const u16* r0 = P0 + (size_t)tok * NCOL;
    const u16* r1 = P1 + (size_t)tok * NCOL;
    const int qoff = (hh * 4 + g) * 16;

    // q row = P0 + P1 + bias, then RMSNorm
    float q[16];
    float ss = 0.f;
    {
        int4 a0 = *(const int4*)(r0 + qoff);
        int4 a1 = *(const int4*)(r0 + qoff + 8);
        int4 b0 = *(const int4*)(r1 + qoff);
        int4 b1 = *(const int4*)(r1 + qoff + 8);
        const int* aw = (const int*)&a0;   // a0,a1 contiguous? no - handle separately
        int wa[8] = {a0.x, a0.y, a0.z, a0.w, a1.x, a1.y, a1.z, a1.w};
        int wb[8] = {b0.x, b0.y, b0.z, b0.w, b1.x, b1.y, b1.z, b1.w};
        (void)aw;
        #pragma unroll
        for (int i = 0; i < 8; ++i) {
            unsigned ua = (unsigned)wa[i], ub = (unsigned)wb[i];
            q[2*i+0] = bfu(ua & 0xFFFFu) + bfu(ub & 0xFFFFu) + sqb[qoff + 2*i+0];
            q[2*i+1] = bfu(ua >> 16)     + bfu(ub >> 16)     + sqb[qoff + 2*i+1];
        }
        #pragma unroll
        for (int d = 0; d < 16; ++d) ss += q[d] * q[d];
    }
    float rq = rsqrtf(ss * (1.f / 16.f) + 1e-6f);
    #pragma unroll
    for (int d = 0; d < 16; ++d) q[d] *= rq * snw[d];

    // k row, RMSNorm
    float k[16];
    float sk = 0.f;
    {
        const int koffb = NQ + hh * 16;
        int4 a0 = *(const int4*)(r0 + koffb);
        int4 a1 = *(const int4*)(r0 + koffb + 8);
        int4 b0 = *(const int4*)(r1 + koffb);
        int4 b1 = *(const int4*)(r1 + koffb + 8);
        int wa[8] = {a0.x, a0.y, a0.z, a0.w, a1.x, a1.y, a1.z, a1.w};
        int wb[8] = {b0.x, b0.y, b0.z, b0.w, b1.x, b1.y, b1.z, b1.w};
        #pragma unroll
        for (int i = 0; i < 8; ++i) {
            unsigned ua = (unsigned)wa[i], ub = (unsigned)wb[i];
            k[2*i+0] = bfu(ua & 0xFFFFu) + bfu(ub & 0xFFFFu);
            k[2*i+1] = bfu(ua >> 16)     + bfu(ub >> 16);
        }
        #pragma unroll
        for (int d = 0; d < 16; ++d) sk += k[d] * k[d];
    }
    float rk = rsqrtf(sk * (1.f / 16.f) + 1e-6f);

    // logit = k̂·q̂ / 4 + b
    float logit = 0.f;
    #pragma unroll
    for (int d = 0; d < 16; ++d) logit += (k[d] * rk * snw[16 + d]) * q[d];
    logit = logit * 0.25f + sb[hh * 4 + g];

    // sum over sink tokens
    float accum = 0.f;
    const float* kbh = skb + hh * 256;
    #pragma unroll
    for (int s = 0; s < 16; ++s) {
        float lb = 0.f;
        #pragma unroll
        for (int d = 0; d < 16; ++d) lb += kbh[s * 16 + d] * q[d];
        accum += __expf(lb * 0.25f - logit);
    }
    float r = 1.f / (1.f + accum);

    // mean over g (4 lanes), lane g==0 writes
    r += __shfl_xor(r, 1);
    r += __shfl_xor(r, 2);
    if (g == 0) out[(size_t)hh * NSEQ + tok] = r * 0.25f;
}

// ---- launch ---------------------------------------------------------------
extern "C" void kernel_launch(void* const* d_in, const int* in_sizes, int n_in,
                              void* d_out, int out_size, void* d_ws, size_t ws_size,
                              hipStream_t stream)
{
    const float* hid = (const float*)d_in[0];
    const float* qw  = (const float*)d_in[1];
    const float* qb  = (const float*)d_in[2];
    const float* kw  = (const float*)d_in[3];
    const float* qnw = (const float*)d_in[4];
    const float* knw = (const float*)d_in[5];
    const float* kb  = (const float*)d_in[6];
    const float* bb  = (const float*)d_in[7];
    float* out = (float*)d_out;

    u16* Wst = (u16*)d_ws;                                        // 5,242,880 B
    u16* P0  = (u16*)((char*)d_ws + (size_t)NCOL * KD * 2);       // 20,971,520 B
    u16* P1  = P0 + (size_t)NSEQ * NCOL;                          // 20,971,520 B

    wconv_kernel<<<TOTAL_CHUNKS / 256, 256, 0, stream>>>(qw, kw, Wst);
    gemm_kernel<<<256, 512, 0, stream>>>(hid, Wst, P0, P1);
    gate_kernel<<<NSEQ * 32 / 256, 256, 0, stream>>>(P0, P1, qb, qnw, knw, kb, bb, out);
}

// Round 3
// 175.470 us; speedup vs baseline: 1.0866x; 1.0645x over previous
//
#include <hip/hip_runtime.h>
#include <hip/hip_bf16.h>

typedef __attribute__((ext_vector_type(8))) short bf16x8;
typedef __attribute__((ext_vector_type(4))) float f32x4;
typedef unsigned short u16;

constexpr int NSEQ = 16384;
constexpr int KD   = 4096;
constexpr int NQ   = 512;     // q cols
constexpr int NCOL = 640;     // q (512) + k (128)
constexpr int BM   = 128;
constexpr int BK   = 32;
constexpr int KHALF = 2048;
constexpr int NKS  = KHALF / BK;                     // 64 K-steps per block
constexpr int CHUNKS_PER_TILE = NCOL * BK * 2 / 16;  // 2560 chunks of 16B
constexpr int NTILES = KD / BK;                      // 128
constexpr int TOTAL_CHUNKS = CHUNKS_PER_TILE * NTILES;
constexpr int TILE_U16 = CHUNKS_PER_TILE * 8;        // 20480 u16 per tile
constexpr int B_BYTES  = 40960;
constexpr int BUF_BYTES = 49152;                     // 40KB B + 8KB A

// ---- f32 -> bf16 (RTNE) pack helpers -------------------------------------
__device__ __forceinline__ unsigned bf_round(float x) {
    unsigned u = __builtin_bit_cast(unsigned, x);
    unsigned r = u + 0x7FFFu + ((u >> 16) & 1u);
    return r >> 16;
}
__device__ __forceinline__ unsigned pk2(float lo, float hi) {
    return bf_round(lo) | (bf_round(hi) << 16);
}
__device__ __forceinline__ float bfu(unsigned u) {
    return __builtin_bit_cast(float, u << 16);
}

// ---- Kernel 1: convert W (q_w ++ k_w) f32 -> bf16, pre-swizzled chunks ----
// Tile kk, chunk c in [0,2560): n = c>>2, s = c&3.
// Position s holds k-slot (s ^ ((n>>1)&3)):  k0 = kk*32 + ((s ^ ((n>>1)&3))<<3)
// Linear glds => LDS: row n, k-slot ks at byte n*64 + ((ks ^ ((n>>1)&3))<<4).
__global__ __launch_bounds__(256) void wconv_kernel(
    const float* __restrict__ qw, const float* __restrict__ kw,
    u16* __restrict__ Wst)
{
    int cg = blockIdx.x * 256 + threadIdx.x;
    int kk = cg / CHUNKS_PER_TILE;
    int c  = cg - kk * CHUNKS_PER_TILE;
    int n  = c >> 2;
    int s  = c & 3;
    int k0 = kk * BK + ((s ^ ((n >> 1) & 3)) << 3);
    const float* src = (n < NQ) ? (qw + (size_t)n * KD + k0)
                                : (kw + (size_t)(n - NQ) * KD + k0);
    float4 v0 = *(const float4*)(src);
    float4 v1 = *(const float4*)(src + 4);
    int4 o;
    o.x = (int)pk2(v0.x, v0.y);
    o.y = (int)pk2(v0.z, v0.w);
    o.z = (int)pk2(v1.x, v1.y);
    o.w = (int)pk2(v1.z, v1.w);
    *(int4*)(Wst + (size_t)cg * 8) = o;
}

// ---- Kernel 2: K-split GEMM, bf16 partial P ------------------------------
// grid 256; XCD b&7 owns K-half (b&7)&1 (W-slice L2-resident per XCD).
// BM=128, BN=640, BK=32; 8 waves (2M x 4N), wave tile 64x160.
// Triple-buffered LDS, glds issued 2 phases ahead, counted vmcnt, raw barrier.
__global__ __launch_bounds__(512, 2) void gemm_kernel(
    const float* __restrict__ hid, const u16* __restrict__ Wst,
    u16* __restrict__ P0, u16* __restrict__ P1)
{
    __shared__ __align__(16) char smem[3 * BUF_BYTES];   // 144 KB

    const int t    = threadIdx.x;
    const int lane = t & 63;
    const int wid  = t >> 6;
    const int wm   = wid >> 2;
    const int wq   = wid & 3;

    const int b    = blockIdx.x;
    const int xcd  = b & 7;
    const int kh   = xcd & 1;
    const int mblk = (b >> 3) * 4 + (xcd >> 1);   // 0..127, bijective
    const int row0 = mblk * BM;

    const float* hk   = hid + (size_t)row0 * KD + kh * KHALF;
    const u16*  wbase = Wst + (size_t)(kh * NKS) * TILE_U16;
    u16* P = kh ? P1 : P0;

    f32x4 acc[4][10] = {};

    // A staging: thread t -> row ar (0..127), k-slot ks8 (0..3), 8 f32
    const int ar  = t >> 2;
    const int ks8 = t & 3;
    const float* gA = hk + (size_t)ar * KD + ks8 * 8;
    const int aWoff = ar * 64 + ((ks8 ^ ((ar >> 1) & 3)) << 4);

    // fragment read params: row = base+bn (base%16==0), kslot = lane>>4
    const int bn    = lane & 15;
    const int kslot = lane >> 4;
    const int koff  = (kslot ^ ((bn >> 1) & 3)) << 4;

    float4 s0a, s0b, s1a, s1b, s2a, s2b;   // 3 A-reg sets (set = x%3)

#define GLDS(X, BW)                                                              \
    do {                                                                         \
        char* sBn_ = smem + (BW) * BUF_BYTES;                                    \
        const u16* tile_ = wbase + (size_t)(X) * TILE_U16;                       \
        _Pragma("unroll")                                                        \
        for (int it = 0; it < 5; ++it)                                           \
            __builtin_amdgcn_global_load_lds(                                    \
                (const __attribute__((address_space(1))) void*)(tile_ + (size_t)(it * 512 + t) * 8), \
                (__attribute__((address_space(3))) void*)(sBn_ + wid * 1024 + it * 8192), \
                16, 0, 0);                                                       \
    } while (0)

#define DSWA(BW, Ra, Rb)                                                         \
    do {                                                                         \
        int4 ap_;                                                                \
        ap_.x = (int)pk2(Ra.x, Ra.y);                                            \
        ap_.y = (int)pk2(Ra.z, Ra.w);                                            \
        ap_.z = (int)pk2(Rb.x, Rb.y);                                            \
        ap_.w = (int)pk2(Rb.z, Rb.w);                                            \
        *(int4*)(smem + (BW) * BUF_BYTES + B_BYTES + aWoff) = ap_;               \
    } while (0)

#define COMPUTE(BC)                                                              \
    do {                                                                         \
        char* sBc_ = smem + (BC) * BUF_BYTES;                                    \
        char* sAc_ = sBc_ + B_BYTES;                                             \
        bf16x8 af_[4];                                                           \
        _Pragma("unroll")                                                        \
        for (int m = 0; m < 4; ++m)                                              \
            af_[m] = *(const bf16x8*)(sAc_ + (wm * 64 + m * 16 + bn) * 64 + koff); \
        _Pragma("unroll")                                                        \
        for (int f = 0; f < 10; ++f) {                                           \
            bf16x8 bfr_ = *(const bf16x8*)(sBc_ + (wq * 160 + f * 16 + bn) * 64 + koff); \
            _Pragma("unroll")                                                    \
            for (int m = 0; m < 4; ++m)                                          \
                acc[m][f] = __builtin_amdgcn_mfma_f32_16x16x32_bf16(af_[m], bfr_, acc[m][f], 0, 0, 0); \
        }                                                                        \
    } while (0)

#define ALOAD(X, Ra, Rb)                                                         \
    do {                                                                         \
        Ra = *(const float4*)(gA + (X) * BK);                                    \
        Rb = *(const float4*)(gA + (X) * BK + 4);                                \
    } while (0)

#define BARR()                                                                   \
    do {                                                                         \
        asm volatile("s_waitcnt lgkmcnt(0)" ::: "memory");                       \
        __builtin_amdgcn_s_barrier();                                            \
    } while (0)

    // ---- prologue: SA0,SA1,SA2; SW(0); SA3; SW(1) ----
    ALOAD(0, s0a, s0b);
    ALOAD(1, s1a, s1b);
    ALOAD(2, s2a, s2b);
    GLDS(0, 0);
    DSWA(0, s0a, s0b);          // implicit vmcnt drains SA0 only
    ALOAD(3, s0a, s0b);
    GLDS(1, 1);
    DSWA(1, s1a, s1b);          // implicit vmcnt(14): drains SA1 only
    BARR();

    // ---- steady: tt = 0..59, 20 iterations x 3 steps ----
    // step tt: ALOAD(tt+4) -> set (tt+1)%3 ; GLDS(tt+2) -> buf (tt+2)%3 ;
    //          DSWA consumes set (tt+2)%3 ; vmcnt(14) ; COMPUTE(tt%3) ; barrier
#pragma unroll 1
    for (int t3 = 0; t3 < 20; ++t3) {
        const int tt = t3 * 3;
        // step tt+0: BC=0 BW=2 load->s1 consume s2
        ALOAD(tt + 4, s1a, s1b);
        GLDS(tt + 2, 2);
        DSWA(2, s2a, s2b);
        asm volatile("s_waitcnt vmcnt(14)" ::: "memory");
        COMPUTE(0);
        BARR();
        // step tt+1: BC=1 BW=0 load->s2 consume s0
        ALOAD(tt + 5, s2a, s2b);
        GLDS(tt + 3, 0);
        DSWA(0, s0a, s0b);
        asm volatile("s_waitcnt vmcnt(14)" ::: "memory");
        COMPUTE(1);
        BARR();
        // step tt+2: BC=2 BW=1 load->s0 consume s1
        ALOAD(tt + 6, s0a, s0b);
        GLDS(tt + 4, 1);
        DSWA(1, s1a, s1b);
        asm volatile("s_waitcnt vmcnt(14)" ::: "memory");
        COMPUTE(2);
        BARR();
    }

    // ---- tail: tt = 60..63 ----
    // tt=60: BC=0 BW=2 consume s2 (A62)
    GLDS(62, 2);
    DSWA(2, s2a, s2b);
    asm volatile("s_waitcnt vmcnt(12)" ::: "memory");
    COMPUTE(0);
    BARR();
    // tt=61: BC=1 BW=0 consume s0 (A63)
    GLDS(63, 0);
    DSWA(0, s0a, s0b);
    asm volatile("s_waitcnt vmcnt(10)" ::: "memory");
    COMPUTE(1);
    BARR();
    // tt=62: BC=2
    asm volatile("s_waitcnt vmcnt(5)" ::: "memory");
    COMPUTE(2);
    BARR();
    // tt=63: BC=0
    asm volatile("s_waitcnt vmcnt(0)" ::: "memory");
    COMPUTE(0);

#undef GLDS
#undef DSWA
#undef COMPUTE
#undef ALOAD
#undef BARR

    // epilogue: bf16 partial-P write. C/D: col=lane&15, row=(lane>>4)*4+j
    const int crow = (lane >> 4) << 2;
    const int ccol = lane & 15;
    u16* Pp = P + (size_t)(row0 + wm * 64) * NCOL + wq * 160 + ccol;
    #pragma unroll
    for (int m = 0; m < 4; ++m)
        #pragma unroll
        for (int f = 0; f < 10; ++f)
            #pragma unroll
            for (int j = 0; j < 4; ++j)
                Pp[(size_t)(m * 16 + crow + j) * NCOL + f * 16] =
                    (u16)bf_round(acc[m][f][j]);
}

// ---- Kernel 3: gating epilogue (reads two bf16 partial-P halves) ----------
__global__ __launch_bounds__(256) void gate_kernel(
    const u16* __restrict__ P0, const u16* __restrict__ P1,
    const float* __restrict__ qb,
    const float* __restrict__ qnw, const float* __restrict__ knw,
    const float* __restrict__ kbase, const float* __restrict__ bb,
    float* __restrict__ out)
{
    __shared__ float skb[8 * 16 * 16];
    __shared__ float sqb[512];
    __shared__ float sb[32];
    __shared__ float snw[32];

    int tid = threadIdx.x;
    for (int i = tid; i < 2048; i += 256) skb[i] = kbase[i];
    for (int i = tid; i < 512;  i += 256) sqb[i] = qb[i];
    if (tid < 32) sb[tid] = bb[tid];
    if (tid < 16) snw[tid] = qnw[tid];
    else if (tid < 32) snw[tid] = knw[tid - 16];
    __syncthreads();

    int gid = blockIdx.x * 256 + tid;
    int tok = gid >> 5;
    int hh  = (gid >> 2) & 7;
    int g   = gid & 3;

    const u16* r0 = P0 + (size_t)tok * NCOL;
    const u16* r1 = P1 + (size_t)tok * NCOL;
    const int qoff = (hh * 4 + g) * 16;

    // q row = P0 + P1 + bias, then RMSNorm
    float q[16];
    float ss = 0.f;
    {
        int4 a0 = *(const int4*)(r0 + qoff);
        int4 a1 = *(const int4*)(r0 + qoff + 8);
        int4 b0 = *(const int4*)(r1 + qoff);
        int4 b1 = *(const int4*)(r1 + qoff + 8);
        int wa[8] = {a0.x, a0.y, a0.z, a0.w, a1.x, a1.y, a1.z, a1.w};
        int wb[8] = {b0.x, b0.y, b0.z, b0.w, b1.x, b1.y, b1.z, b1.w};
        #pragma unroll
        for (int i = 0; i < 8; ++i) {
            unsigned ua = (unsigned)wa[i], ub = (unsigned)wb[i];
            q[2*i+0] = bfu(ua & 0xFFFFu) + bfu(ub & 0xFFFFu) + sqb[qoff + 2*i+0];
            q[2*i+1] = bfu(ua >> 16)     + bfu(ub >> 16)     + sqb[qoff + 2*i+1];
        }
        #pragma unroll
        for (int d = 0; d < 16; ++d) ss += q[d] * q[d];
    }
    float rq = rsqrtf(ss * (1.f / 16.f) + 1e-6f);
    #pragma unroll
    for (int d = 0; d < 16; ++d) q[d] *= rq * snw[d];

    // k row, RMSNorm
    float k[16];
    float sk = 0.f;
    {
        const int koffb = NQ + hh * 16;
        int4 a0 = *(const int4*)(r0 + koffb);
        int4 a1 = *(const int4*)(r0 + koffb + 8);
        int4 b0 = *(const int4*)(r1 + koffb);
        int4 b1 = *(const int4*)(r1 + koffb + 8);
        int wa[8] = {a0.x, a0.y, a0.z, a0.w, a1.x, a1.y, a1.z, a1.w};
        int wb[8] = {b0.x, b0.y, b0.z, b0.w, b1.x, b1.y, b1.z, b1.w};
        #pragma unroll
        for (int i = 0; i < 8; ++i) {
            unsigned ua = (unsigned)wa[i], ub = (unsigned)wb[i];
            k[2*i+0] = bfu(ua & 0xFFFFu) + bfu(ub & 0xFFFFu);
            k[2*i+1] = bfu(ua >> 16)     + bfu(ub >> 16);
        }
        #pragma unroll
        for (int d = 0; d < 16; ++d) sk += k[d] * k[d];
    }
    float rk = rsqrtf(sk * (1.f / 16.f) + 1e-6f);

    // logit = k̂·q̂ / 4 + b
    float logit = 0.f;
    #pragma unroll
    for (int d = 0; d < 16; ++d) logit += (k[d] * rk * snw[16 + d]) * q[d];
    logit = logit * 0.25f + sb[hh * 4 + g];

    // sum over sink tokens
    float accum = 0.f;
    const float* kbh = skb + hh * 256;
    #pragma unroll
    for (int s = 0; s < 16; ++s) {
        float lb = 0.f;
        #pragma unroll
        for (int d = 0; d < 16; ++d) lb += kbh[s * 16 + d] * q[d];
        accum += __expf(lb * 0.25f - logit);
    }
    float r = 1.f / (1.f + accum);

    // mean over g (4 lanes), lane g==0 writes
    r += __shfl_xor(r, 1);
    r += __shfl_xor(r, 2);
    if (g == 0) out[(size_t)hh * NSEQ + tok] = r * 0.25f;
}

// ---- launch ---------------------------------------------------------------
extern "C" void kernel_launch(void* const* d_in, const int* in_sizes, int n_in,
                              void* d_out, int out_size, void* d_ws, size_t ws_size,
                              hipStream_t stream)
{
    const float* hid = (const float*)d_in[0];
    const float* qw  = (const float*)d_in[1];
    const float* qb  = (const float*)d_in[2];
    const float* kw  = (const float*)d_in[3];
    const float* qnw = (const float*)d_in[4];
    const float* knw = (const float*)d_in[5];
    const float* kb  = (const float*)d_in[6];
    const float* bb  = (const float*)d_in[7];
    float* out = (float*)d_out;

    u16* Wst = (u16*)d_ws;                                        // 5,242,880 B
    u16* P0  = (u16*)((char*)d_ws + (size_t)NCOL * KD * 2);       // 20,971,520 B
    u16* P1  = P0 + (size_t)NSEQ * NCOL;                          // 20,971,520 B

    wconv_kernel<<<TOTAL_CHUNKS / 256, 256, 0, stream>>>(qw, kw, Wst);
    gemm_kernel<<<256, 512, 0, stream>>>(hid, Wst, P0, P1);
    gate_kernel<<<NSEQ * 32 / 256, 256, 0, stream>>>(P0, P1, qb, qnw, knw, kb, bb, out);
}